// Round 1
// 507.980 us; speedup vs baseline: 1.0035x; 1.0035x over previous
//
#include <hip/hip_runtime.h>
#include <math.h>

namespace {
constexpr int B = 8, L = 200, H = 128, NH = 4;
constexpr int LP = 224;                            // padded row count (zeroed tail)
constexpr int LPAD = 228;                          // p row stride: 228%32=4 -> heads hit distinct banks
constexpr float NEG = -4294967295.0f;              // -(2^32)+1
constexpr float QSCALE = 0.17677669529663687f;     // 1/sqrt(32)
}

// ---------------------------------------------------------------------------
// Kernel 1: Q/K/V projections (nn.Linear: y = x @ W.T + b), fused with
//   Q *= 1/sqrt(HD);  K += abs_pos_K;  V += abs_pos_V.   (unchanged)
// ---------------------------------------------------------------------------
extern "C" __global__ __launch_bounds__(256) void tama_proj(
    const float* __restrict__ queries, const float* __restrict__ keys,
    const float* __restrict__ apK, const float* __restrict__ apV,
    const float* __restrict__ Wq, const float* __restrict__ bq,
    const float* __restrict__ Wk, const float* __restrict__ bk,
    const float* __restrict__ Wv, const float* __restrict__ bv,
    float* __restrict__ Qs, float* __restrict__ KpK, float* __restrict__ VpV)
{
    const int nrb = (B * L) / 8;            // 200 row-blocks per projection
    const int which = blockIdx.x / nrb;     // 0:Q 1:K 2:V
    const int r0 = (blockIdx.x % nrb) * 8;
    const int t = threadIdx.x;

    const float* __restrict__ x    = (which == 0) ? queries : keys;
    const float* __restrict__ W    = (which == 0) ? Wq : (which == 1) ? Wk : Wv;
    const float* __restrict__ bias = (which == 0) ? bq : (which == 1) ? bk : bv;

    __shared__ float xs[8][H];
    *(float4*)(&xs[0][0] + t * 4) = *(const float4*)(x + (size_t)r0 * H + t * 4);
    __syncthreads();

    const int d  = t & (H - 1);
    const int rh = (t >> 7) * 4;            // local row base: 0 or 4
    float a0 = 0.f, a1 = 0.f, a2 = 0.f, a3 = 0.f;
    const float4* __restrict__ wrow4 = (const float4*)(W + (size_t)d * H);
    #pragma unroll 8
    for (int j4 = 0; j4 < H / 4; ++j4) {
        const float4 w = wrow4[j4];
        const int j = j4 * 4;
        a0 += xs[rh + 0][j] * w.x + xs[rh + 0][j + 1] * w.y
            + xs[rh + 0][j + 2] * w.z + xs[rh + 0][j + 3] * w.w;
        a1 += xs[rh + 1][j] * w.x + xs[rh + 1][j + 1] * w.y
            + xs[rh + 1][j + 2] * w.z + xs[rh + 1][j + 3] * w.w;
        a2 += xs[rh + 2][j] * w.x + xs[rh + 2][j + 1] * w.y
            + xs[rh + 2][j + 2] * w.z + xs[rh + 2][j + 3] * w.w;
        a3 += xs[rh + 3][j] * w.x + xs[rh + 3][j + 1] * w.y
            + xs[rh + 3][j + 2] * w.z + xs[rh + 3][j + 3] * w.w;
    }
    const float bb = bias[d];
    float o[4] = {a0 + bb, a1 + bb, a2 + bb, a3 + bb};

    if (which == 0) {
        #pragma unroll
        for (int rr = 0; rr < 4; ++rr)
            Qs[(size_t)(r0 + rh + rr) * H + d] = o[rr] * QSCALE;
    } else if (which == 1) {
        #pragma unroll
        for (int rr = 0; rr < 4; ++rr) {
            const size_t idx = (size_t)(r0 + rh + rr) * H + d;
            KpK[idx] = o[rr] + apK[idx];
        }
    } else {
        #pragma unroll
        for (int rr = 0; rr < 4; ++rr) {
            const size_t idx = (size_t)(r0 + rh + rr) * H + d;
            VpV[idx] = o[rr] + apV[idx];
        }
    }
}

// ---------------------------------------------------------------------------
// Direct global->LDS DMA, 16B per lane. LDS dest is wave-uniform base +
// lane*16 (m104); global source is per-lane. Zero destination VGPRs, so the
// compiler cannot serialize the pipeline for register-pressure reasons.
// ---------------------------------------------------------------------------
__device__ __forceinline__ void gll16(const float* g, float* l)
{
    __builtin_amdgcn_global_load_lds(
        (const __attribute__((address_space(1))) void*)g,
        (__attribute__((address_space(3))) void*)l, 16, 0, 0);
}

// One stage for one wave: 4 rows x 3 streams = 6 KB = 6 DMA instructions.
// Lane l sources row (k0+rb) [rb = 4w+ri, ri=l>>5] col (l&31)*4; rows are
// contiguous so each instruction covers exactly 2 rows of one stream.
// dst layout per (buf,wave): [stream(3)][row(4)][col(128)] floats.
__device__ __forceinline__ void issue3(
    const float* __restrict__ sA, const float* __restrict__ sC,
    const float* __restrict__ sE, int k0, int rb, int cg, float* dst)
{
    int r0 = k0 + rb;          // rows 2i+{0,1} of this wave's 4-row group
    int r1 = r0 + 2;           // rows 2i+{2,3}
    r0 = r0 < L ? r0 : L - 1;  // clamp: harmless in-bounds read, p guards output
    r1 = r1 < L ? r1 : L - 1;
    const size_t o0 = (size_t)r0 * H + (cg << 2);
    const size_t o1 = (size_t)r1 * H + (cg << 2);
    gll16(sA + o0, dst);
    gll16(sA + o1, dst + 256);
    gll16(sC + o0, dst + 512);
    gll16(sC + o1, dst + 768);
    gll16(sE + o0, dst + 1024);
    gll16(sE + o1, dst + 1280);
}

// ---------------------------------------------------------------------------
// Kernel 2: fused attention. One block per (b,q), 4 waves; wave w privately
// streams rows {16s+4w .. 16s+4w+3} of (tK,dK,K') / (tV,dV,V') through its
// own double-buffered LDS region via global_load_lds with counted vmcnt:
// steady state keeps 6-12 x 1KB loads in flight per wave, never draining to
// vmcnt(0) inside the k-loop. No block barriers inside the k-loops.
// LDS: 48KB staging + 3.6KB probs = 52.8KB -> 3 blocks/CU (12 waves).
// ---------------------------------------------------------------------------
extern "C" __global__ __launch_bounds__(256, 3) void tama_attn(
    const float* __restrict__ Qs, const float* __restrict__ KpK,
    const float* __restrict__ VpV, const int* __restrict__ time_mask,
    const float* __restrict__ tK, const float* __restrict__ tV,
    const float* __restrict__ dK, const float* __restrict__ dV,
    float* __restrict__ out)
{
    const int bq = (int)gridDim.x - 1 - (int)blockIdx.x;  // heavy (high-q) first
    const int b = bq / L, q = bq - b * L;
    const int t = threadIdx.x;

    __shared__ float stg[2][4][3][4][128];  // 48 KB: [buf][wave][stream][row][col]
    __shared__ float p[NH][LPAD];           // probs, stride-padded (bank-spread)

    const int lane = t & 63;
    const int w    = t >> 6;         // wave 0..3
    const int ri   = lane >> 5;      // row-in-pair 0/1
    const int cg   = lane & 31;      // column group (float4)
    const int c4   = cg << 2;
    const int h    = cg >> 3;        // head 0..3
    const int sg   = lane & 7;
    const int rb   = (w << 2) + ri;  // this thread's row base within a stage

    const bool tmq = time_mask[b * L + q] != 0;  // row-mask: whole q row NEG
    const int kA = tmq ? 0 : (q + 1);            // score phase extent
    const int kB = tmq ? L : (q + 1);            // output phase extent

    const float4 q4 = *(const float4*)(Qs + (size_t)bq * H + c4);
    const float* __restrict__ tKb = tK + (size_t)bq * L * H;
    const float* __restrict__ dKb = dK + (size_t)bq * L * H;
    const float* __restrict__ kpb = KpK + (size_t)b * L * H;
    const float* __restrict__ tVb = tV + (size_t)bq * L * H;
    const float* __restrict__ dVb = dV + (size_t)bq * L * H;
    const float* __restrict__ vpb = VpV + (size_t)b * L * H;

    float* const st0 = &stg[0][w][0][0][0];
    float* const st1 = &stg[1][w][0][0][0];

    // ---- Phase A: scores. Per-wave pipelined DMA, vmcnt(6) steady state ----
    const int nstA = (kA + 15) >> 4;
    if (nstA > 0) {
        issue3(tKb, dKb, kpb, 0, rb, cg, st0);
        for (int s = 0; s < nstA; ++s) {
            const float* rd = (s & 1) ? st1 : st0;
            if (s + 1 < nstA) {
                issue3(tKb, dKb, kpb, (s + 1) << 4, rb, cg,
                       ((s + 1) & 1) ? st1 : st0);
                asm volatile("s_waitcnt vmcnt(6)" ::: "memory");
            } else {
                asm volatile("s_waitcnt vmcnt(0)" ::: "memory");
            }
            __builtin_amdgcn_sched_barrier(0);
            const float4 a0  = *(const float4*)(rd + ri * 128 + c4);
            const float4 a1  = *(const float4*)(rd + (ri + 2) * 128 + c4);
            const float4 cc0 = *(const float4*)(rd + 512 + ri * 128 + c4);
            const float4 cc1 = *(const float4*)(rd + 512 + (ri + 2) * 128 + c4);
            const float4 e0  = *(const float4*)(rd + 1024 + ri * 128 + c4);
            const float4 e1  = *(const float4*)(rd + 1024 + (ri + 2) * 128 + c4);
            float s0 = q4.x * (a0.x + cc0.x + e0.x)
                     + q4.y * (a0.y + cc0.y + e0.y)
                     + q4.z * (a0.z + cc0.z + e0.z)
                     + q4.w * (a0.w + cc0.w + e0.w);
            float s1 = q4.x * (a1.x + cc1.x + e1.x)
                     + q4.y * (a1.y + cc1.y + e1.y)
                     + q4.z * (a1.z + cc1.z + e1.z)
                     + q4.w * (a1.w + cc1.w + e1.w);
            s0 += __shfl_xor(s0, 1); s0 += __shfl_xor(s0, 2); s0 += __shfl_xor(s0, 4);
            s1 += __shfl_xor(s1, 1); s1 += __shfl_xor(s1, 2); s1 += __shfl_xor(s1, 4);
            const int ku0 = (s << 4) + rb;
            if (sg == 0 && ku0 <= q)     p[h][ku0] = s0;
            if (sg == 0 && ku0 + 2 <= q) p[h][ku0 + 2] = s1;
        }
    }

    // Prefetch phase-B stage 0 NOW; raw barriers below don't drain vmcnt, so
    // its latency hides under the softmax.
    asm volatile("s_waitcnt lgkmcnt(0)" ::: "memory");  // phase-A LDS reads done
    issue3(tVb, dVb, vpb, 0, rb, cg, st0);
    __builtin_amdgcn_s_barrier();
    asm volatile("" ::: "memory");

    // ---- Softmax: wave w handles head w; lanes cover k = lane + 64*i ----
    {
        float s0 = p[w][lane];
        float s1 = p[w][lane + 64];
        float s2 = p[w][lane + 128];
        float s3 = (lane < L - 192) ? p[w][lane + 192] : NEG;
        if (tmq || lane > q)       s0 = NEG;
        if (tmq || lane + 64 > q)  s1 = NEG;
        if (tmq || lane + 128 > q) s2 = NEG;
        if (tmq || lane + 192 > q) s3 = NEG;   // always true for lane >= 8
        float m = fmaxf(fmaxf(s0, s1), fmaxf(s2, s3));
        #pragma unroll
        for (int off = 32; off; off >>= 1) m = fmaxf(m, __shfl_xor(m, off));
        const float e0 = __expf(s0 - m);       // exp(NEG-m) underflows to 0.0f
        const float e1 = __expf(s1 - m);
        const float e2 = __expf(s2 - m);
        const float e3 = (lane < L - 192) ? __expf(s3 - m) : 0.f;
        float sum = e0 + e1 + e2 + e3;
        #pragma unroll
        for (int off = 32; off; off >>= 1) sum += __shfl_xor(sum, off);
        const float inv = 1.0f / sum;
        p[w][lane]       = e0 * inv;
        p[w][lane + 64]  = e1 * inv;
        p[w][lane + 128] = e2 * inv;
        if (lane < L - 192) p[w][lane + 192] = e3 * inv;
        if (lane < LP - L)  p[w][L + lane] = 0.f;   // zero pad 200..223
    }
    asm volatile("s_waitcnt lgkmcnt(0)" ::: "memory");
    __builtin_amdgcn_s_barrier();
    asm volatile("" ::: "memory");

    // ---- Phase B: out[c] = sum_k p[h][k] * (VpV + tV + dV)[k][c] ----
    float ax = 0.f, ay = 0.f, az = 0.f, aw = 0.f;
    const int nstB = (kB + 15) >> 4;
    for (int s = 0; s < nstB; ++s) {
        const float* rd = (s & 1) ? st1 : st0;
        if (s + 1 < nstB) {
            issue3(tVb, dVb, vpb, (s + 1) << 4, rb, cg,
                   ((s + 1) & 1) ? st1 : st0);
            asm volatile("s_waitcnt vmcnt(6)" ::: "memory");
        } else {
            asm volatile("s_waitcnt vmcnt(0)" ::: "memory");
        }
        __builtin_amdgcn_sched_barrier(0);
        const int ku0 = (s << 4) + rb;
        const float pk0 = p[h][ku0];          // 0 beyond kB (softmax zeroed)
        const float pk1 = p[h][ku0 + 2];
        const float4 a0  = *(const float4*)(rd + ri * 128 + c4);
        const float4 a1  = *(const float4*)(rd + (ri + 2) * 128 + c4);
        const float4 cc0 = *(const float4*)(rd + 512 + ri * 128 + c4);
        const float4 cc1 = *(const float4*)(rd + 512 + (ri + 2) * 128 + c4);
        const float4 e0  = *(const float4*)(rd + 1024 + ri * 128 + c4);
        const float4 e1  = *(const float4*)(rd + 1024 + (ri + 2) * 128 + c4);
        ax += pk0 * (a0.x + cc0.x + e0.x) + pk1 * (a1.x + cc1.x + e1.x);
        ay += pk0 * (a0.y + cc0.y + e0.y) + pk1 * (a1.y + cc1.y + e1.y);
        az += pk0 * (a0.z + cc0.z + e0.z) + pk1 * (a1.z + cc1.z + e1.z);
        aw += pk0 * (a0.w + cc0.w + e0.w) + pk1 * (a1.w + cc1.w + e1.w);
    }

    // ---- Cross-wave column reduction; scratch aliases the (drained) staging
    // buffer to keep LDS under the 3-blocks/CU threshold. ----
    __syncthreads();   // all waves done reading stg; all DMAs drained (vmcnt 0)
    {
        float* red = &stg[0][0][0][0][0];     // [8][H] reuse
        float* rr = red + ((w << 1) + ri) * H + c4;
        rr[0] = ax; rr[1] = ay; rr[2] = az; rr[3] = aw;
    }
    __syncthreads();
    if (t < 32) {
        const float* red = &stg[0][0][0][0][0];
        float4 r = {0.f, 0.f, 0.f, 0.f};
        #pragma unroll
        for (int j = 0; j < 8; ++j) {
            r.x += red[j * H + t * 4 + 0];
            r.y += red[j * H + t * 4 + 1];
            r.z += red[j * H + t * 4 + 2];
            r.w += red[j * H + t * 4 + 3];
        }
        *(float4*)(out + (size_t)bq * H + t * 4) = r;
    }
}

// ---------------------------------------------------------------------------
extern "C" void kernel_launch(void* const* d_in, const int* in_sizes, int n_in,
                              void* d_out, int out_size, void* d_ws, size_t ws_size,
                              hipStream_t stream)
{
    const float* queries   = (const float*)d_in[0];
    const float* keys      = (const float*)d_in[1];
    const int*   time_mask = (const int*)d_in[2];
    // d_in[3] attn_mask unused: it is exactly triu(ones, k=1), i.e. (k > q)
    const float* tK  = (const float*)d_in[4];
    const float* tV  = (const float*)d_in[5];
    const float* dK  = (const float*)d_in[6];
    const float* dV  = (const float*)d_in[7];
    const float* apK = (const float*)d_in[8];
    const float* apV = (const float*)d_in[9];
    const float* Wq  = (const float*)d_in[10];
    const float* bqv = (const float*)d_in[11];
    const float* Wk  = (const float*)d_in[12];
    const float* bkv = (const float*)d_in[13];
    const float* Wv  = (const float*)d_in[14];
    const float* bvv = (const float*)d_in[15];

    float* Qs  = (float*)d_ws;                 // [B*L*H]
    float* KpK = Qs + (size_t)B * L * H;       // [B*L*H]
    float* VpV = KpK + (size_t)B * L * H;      // [B*L*H]  (total 2.46 MB)
    float* outp = (float*)d_out;

    hipLaunchKernelGGL(tama_proj, dim3(3 * (B * L) / 8), dim3(256), 0, stream,
                       queries, keys, apK, apV, Wq, bqv, Wk, bkv, Wv, bvv,
                       Qs, KpK, VpV);
    hipLaunchKernelGGL(tama_attn, dim3(B * L), dim3(256), 0, stream,
                       Qs, KpK, VpV, time_mask, tK, tV, dK, dV, outp);
}

// Round 2
// 506.726 us; speedup vs baseline: 1.0060x; 1.0025x over previous
//
#include <hip/hip_runtime.h>
#include <math.h>
#include <stdint.h>

namespace {
constexpr int B = 8, L = 200, H = 128, NH = 4;
constexpr int LP = 224;                            // padded row count (zeroed tail)
constexpr int LPAD = 228;                          // p row stride (bank-spread)
constexpr float NEG = -4294967295.0f;              // -(2^32)+1
constexpr float QSCALE = 0.17677669529663687f;     // 1/sqrt(32)
}

typedef __attribute__((ext_vector_type(4))) int   int4v;
typedef __attribute__((ext_vector_type(4))) float float4v;

// ---------------------------------------------------------------------------
// Kernel 1: Q/K/V projections (nn.Linear: y = x @ W.T + b), fused with
//   Q *= 1/sqrt(HD);  K += abs_pos_K;  V += abs_pos_V.   (unchanged)
// ---------------------------------------------------------------------------
extern "C" __global__ __launch_bounds__(256) void tama_proj(
    const float* __restrict__ queries, const float* __restrict__ keys,
    const float* __restrict__ apK, const float* __restrict__ apV,
    const float* __restrict__ Wq, const float* __restrict__ bq,
    const float* __restrict__ Wk, const float* __restrict__ bk,
    const float* __restrict__ Wv, const float* __restrict__ bv,
    float* __restrict__ Qs, float* __restrict__ KpK, float* __restrict__ VpV)
{
    const int nrb = (B * L) / 8;            // 200 row-blocks per projection
    const int which = blockIdx.x / nrb;     // 0:Q 1:K 2:V
    const int r0 = (blockIdx.x % nrb) * 8;
    const int t = threadIdx.x;

    const float* __restrict__ x    = (which == 0) ? queries : keys;
    const float* __restrict__ W    = (which == 0) ? Wq : (which == 1) ? Wk : Wv;
    const float* __restrict__ bias = (which == 0) ? bq : (which == 1) ? bk : bv;

    __shared__ float xs[8][H];
    *(float4*)(&xs[0][0] + t * 4) = *(const float4*)(x + (size_t)r0 * H + t * 4);
    __syncthreads();

    const int d  = t & (H - 1);
    const int rh = (t >> 7) * 4;            // local row base: 0 or 4
    float a0 = 0.f, a1 = 0.f, a2 = 0.f, a3 = 0.f;
    const float4* __restrict__ wrow4 = (const float4*)(W + (size_t)d * H);
    #pragma unroll 8
    for (int j4 = 0; j4 < H / 4; ++j4) {
        const float4 w = wrow4[j4];
        const int j = j4 * 4;
        a0 += xs[rh + 0][j] * w.x + xs[rh + 0][j + 1] * w.y
            + xs[rh + 0][j + 2] * w.z + xs[rh + 0][j + 3] * w.w;
        a1 += xs[rh + 1][j] * w.x + xs[rh + 1][j + 1] * w.y
            + xs[rh + 1][j + 2] * w.z + xs[rh + 1][j + 3] * w.w;
        a2 += xs[rh + 2][j] * w.x + xs[rh + 2][j + 1] * w.y
            + xs[rh + 2][j + 2] * w.z + xs[rh + 2][j + 3] * w.w;
        a3 += xs[rh + 3][j] * w.x + xs[rh + 3][j + 1] * w.y
            + xs[rh + 3][j + 2] * w.z + xs[rh + 3][j + 3] * w.w;
    }
    const float bb = bias[d];
    float o[4] = {a0 + bb, a1 + bb, a2 + bb, a3 + bb};

    if (which == 0) {
        #pragma unroll
        for (int rr = 0; rr < 4; ++rr)
            Qs[(size_t)(r0 + rh + rr) * H + d] = o[rr] * QSCALE;
    } else if (which == 1) {
        #pragma unroll
        for (int rr = 0; rr < 4; ++rr) {
            const size_t idx = (size_t)(r0 + rh + rr) * H + d;
            KpK[idx] = o[rr] + apK[idx];
        }
    } else {
        #pragma unroll
        for (int rr = 0; rr < 4; ++rr) {
            const size_t idx = (size_t)(r0 + rh + rr) * H + d;
            VpV[idx] = o[rr] + apV[idx];
        }
    }
}

// ---------------------------------------------------------------------------
// SRSRC buffer descriptor: stride=0 raw, num_records = valid BYTES.
// OOB lanes (voffset+imm+16 > num_records) return 0 and generate NO memory
// traffic -> exact triangular bounds + free unconditional prefetch past end.
// ---------------------------------------------------------------------------
__device__ __forceinline__ int4v mk_srsrc(const float* p, int bytes)
{
    int4v r;
    r.x = (int)(uint32_t)(uint64_t)p;
    r.y = (int)(((uint64_t)p >> 32) & 0xFFFFu);   // base[47:32], stride=0
    r.z = bytes;                                  // num_records (bytes)
    r.w = 0x00020000;                             // raw dword access
    return r;
}

// Inline-asm buffer loads: INVISIBLE to the compiler's waitcnt pass, so it
// cannot insert vmcnt(0) drains in the k-loops; the only waits are ours.
// volatile => never DCE'd (deterministic vmcnt bookkeeping) and kept in order.
__device__ __forceinline__ float4v bl0(int4v d, int vo)
{
    float4v r;
    asm volatile("buffer_load_dwordx4 %0, %1, %2, 0 offen"
                 : "=v"(r) : "v"(vo), "s"(d));
    return r;
}
__device__ __forceinline__ float4v bl1(int4v d, int vo)
{
    float4v r;
    asm volatile("buffer_load_dwordx4 %0, %1, %2, 0 offen offset:1024"
                 : "=v"(r) : "v"(vo), "s"(d));
    return r;
}

// ---------------------------------------------------------------------------
// Kernel 2: fused attention. One block per (b,q), 4 waves. Each wave owns
// rows 16s+4w..16s+4w+3 per macro-step s and keeps a 4-deep VGPR ring of
// 6 buffer_load_dwordx4 per slot (24 KB/wave in flight; ~250 KB/CU at 12
// waves). Steady-state wait is s_waitcnt vmcnt(18) -- never 0 inside loops.
// ---------------------------------------------------------------------------
extern "C" __global__ __launch_bounds__(256, 3) void tama_attn(
    const float* __restrict__ Qs, const float* __restrict__ KpK,
    const float* __restrict__ VpV, const int* __restrict__ time_mask,
    const float* __restrict__ tK, const float* __restrict__ tV,
    const float* __restrict__ dK, const float* __restrict__ dV,
    float* __restrict__ out)
{
    const int bq = (int)gridDim.x - 1 - (int)blockIdx.x;  // heavy (high-q) first
    const int b = bq / L, q = bq - b * L;
    const int t = threadIdx.x;

    __shared__ float p[NH][LPAD];   // probs per head
    __shared__ float red[8][H];     // output reduction scratch

    const int lane = t & 63;
    const int w    = t >> 6;         // wave 0..3
    const int ri   = lane >> 5;      // row-in-pair 0/1
    const int cg   = lane & 31;      // column group (float4)
    const int c4   = cg << 2;
    const int h    = cg >> 3;        // head 0..3
    const int sg   = lane & 7;

    const bool tmq = time_mask[b * L + q] != 0;  // row-mask: whole q row NEG
    const int kA = tmq ? 0 : (q + 1);            // score phase extent (rows)
    const int kB = tmq ? L : (q + 1);            // output phase extent (rows)
    const int nstA = (kA + 15) >> 4;
    const int nstB = (kB + 15) >> 4;

    // lane's byte offset within a macro-step: rows (4w+ri, +1) via lane*16,
    // rows (+2,+3) via offset:1024.  step s adds 8192 bytes (16 rows).
    const int vbase = (w << 11) + (lane << 4);

    const float4v q4 = *(const float4v*)(Qs + (size_t)bq * H + c4);

    const int4v dKa = mk_srsrc(tK  + (size_t)bq * L * H, kA * 512);
    const int4v dDa = mk_srsrc(dK  + (size_t)bq * L * H, kA * 512);
    const int4v dEa = mk_srsrc(KpK + (size_t)b  * L * H, kA * 512);
    const int4v dKb = mk_srsrc(tV  + (size_t)bq * L * H, kB * 512);
    const int4v dDb = mk_srsrc(dV  + (size_t)bq * L * H, kB * 512);
    const int4v dEb = mk_srsrc(VpV + (size_t)b  * L * H, kB * 512);

    // Drain tracked VMEM (q4, time_mask) so compiler-visible vmcnt state is 0
    // before our untracked asm loads begin; it then has no reason to insert
    // any further vmcnt waits in the loops.
    asm volatile("s_waitcnt vmcnt(0)" ::: "memory");
    __builtin_amdgcn_sched_barrier(0);

    float4v rA0[4], rA1[4], rC0[4], rC1[4], rE0[4], rE1[4];

    // ---- Phase A: scores ----
    if (nstA > 0) {
        #pragma unroll
        for (int j = 0; j < 4; ++j) {               // ring prologue: 24 loads
            const int vo = vbase + j * 8192;
            rA0[j] = bl0(dKa, vo); rA1[j] = bl1(dKa, vo);
            rC0[j] = bl0(dDa, vo); rC1[j] = bl1(dDa, vo);
            rE0[j] = bl0(dEa, vo); rE1[j] = bl1(dEa, vo);
        }
        for (int s0 = 0; s0 < nstA; s0 += 4) {
            #pragma unroll
            for (int j = 0; j < 4; ++j) {
                const int s = s0 + j;
                // oldest slot (j) complete when <=18 of 24 remain
                asm volatile("s_waitcnt vmcnt(18)" ::: "memory");
                __builtin_amdgcn_sched_barrier(0);
                if (s < nstA) {
                    float sv0 = q4.x * (rA0[j].x + rC0[j].x + rE0[j].x)
                              + q4.y * (rA0[j].y + rC0[j].y + rE0[j].y)
                              + q4.z * (rA0[j].z + rC0[j].z + rE0[j].z)
                              + q4.w * (rA0[j].w + rC0[j].w + rE0[j].w);
                    float sv1 = q4.x * (rA1[j].x + rC1[j].x + rE1[j].x)
                              + q4.y * (rA1[j].y + rC1[j].y + rE1[j].y)
                              + q4.z * (rA1[j].z + rC1[j].z + rE1[j].z)
                              + q4.w * (rA1[j].w + rC1[j].w + rE1[j].w);
                    sv0 += __shfl_xor(sv0, 1); sv0 += __shfl_xor(sv0, 2); sv0 += __shfl_xor(sv0, 4);
                    sv1 += __shfl_xor(sv1, 1); sv1 += __shfl_xor(sv1, 2); sv1 += __shfl_xor(sv1, 4);
                    const int ku0 = (s << 4) + (w << 2) + ri;
                    if (sg == 0 && ku0 <= q)     p[h][ku0]     = sv0;
                    if (sg == 0 && ku0 + 2 <= q) p[h][ku0 + 2] = sv1;
                }
                const int vo = vbase + (s + 4) * 8192;   // refill slot j
                rA0[j] = bl0(dKa, vo); rA1[j] = bl1(dKa, vo);
                rC0[j] = bl0(dDa, vo); rC1[j] = bl1(dDa, vo);
                rE0[j] = bl0(dEa, vo); rE1[j] = bl1(dEa, vo);
            }
        }
        // Drain dangling refills: their dest regs are about to be re-issued
        // by the phase-B prologue (WAR on vdst across in-flight loads).
        asm volatile("s_waitcnt vmcnt(0)" ::: "memory");
        __builtin_amdgcn_sched_barrier(0);
    }

    // ---- Phase-B ring prologue BEFORE softmax: 24 loads fly across it ----
    #pragma unroll
    for (int j = 0; j < 4; ++j) {
        const int vo = vbase + j * 8192;
        rA0[j] = bl0(dKb, vo); rA1[j] = bl1(dKb, vo);
        rC0[j] = bl0(dDb, vo); rC1[j] = bl1(dDb, vo);
        rE0[j] = bl0(dEb, vo); rE1[j] = bl1(dEb, vo);
    }

    // Raw barrier (no compiler vmcnt drain): only LDS (p) must be visible.
    asm volatile("s_waitcnt lgkmcnt(0)" ::: "memory");
    __builtin_amdgcn_s_barrier();
    asm volatile("" ::: "memory");

    // ---- Softmax: wave w handles head w; lanes cover k = lane + 64*i ----
    {
        float s0 = p[w][lane];
        float s1 = p[w][lane + 64];
        float s2 = p[w][lane + 128];
        float s3 = (lane < L - 192) ? p[w][lane + 192] : NEG;
        if (tmq || lane > q)       s0 = NEG;
        if (tmq || lane + 64 > q)  s1 = NEG;
        if (tmq || lane + 128 > q) s2 = NEG;
        if (tmq || lane + 192 > q) s3 = NEG;   // always true for lane >= 8
        float m = fmaxf(fmaxf(s0, s1), fmaxf(s2, s3));
        #pragma unroll
        for (int off = 32; off; off >>= 1) m = fmaxf(m, __shfl_xor(m, off));
        const float e0 = __expf(s0 - m);       // exp(NEG-m) underflows to 0.0f
        const float e1 = __expf(s1 - m);
        const float e2 = __expf(s2 - m);
        const float e3 = (lane < L - 192) ? __expf(s3 - m) : 0.f;
        float sum = e0 + e1 + e2 + e3;
        #pragma unroll
        for (int off = 32; off; off >>= 1) sum += __shfl_xor(sum, off);
        const float inv = 1.0f / sum;
        p[w][lane]       = e0 * inv;
        p[w][lane + 64]  = e1 * inv;
        p[w][lane + 128] = e2 * inv;
        if (lane < L - 192) p[w][lane + 192] = e3 * inv;
        if (lane < LP - L)  p[w][L + lane] = 0.f;   // zero pad 200..223
    }
    asm volatile("s_waitcnt lgkmcnt(0)" ::: "memory");
    __builtin_amdgcn_s_barrier();
    asm volatile("" ::: "memory");

    // ---- Phase B: out[c] = sum_k p[h][k] * (VpV + tV + dV)[k][c] ----
    float ax = 0.f, ay = 0.f, az = 0.f, aw = 0.f;
    for (int s0 = 0; s0 < nstB; s0 += 4) {
        #pragma unroll
        for (int j = 0; j < 4; ++j) {
            const int s = s0 + j;
            asm volatile("s_waitcnt vmcnt(18)" ::: "memory");
            __builtin_amdgcn_sched_barrier(0);
            if (s < nstB) {
                const int ku0 = (s << 4) + (w << 2) + ri;
                const float pk0 = p[h][ku0];       // 0 beyond kB (softmax pad)
                const float pk1 = p[h][ku0 + 2];
                ax += pk0 * (rA0[j].x + rC0[j].x + rE0[j].x)
                    + pk1 * (rA1[j].x + rC1[j].x + rE1[j].x);
                ay += pk0 * (rA0[j].y + rC0[j].y + rE0[j].y)
                    + pk1 * (rA1[j].y + rC1[j].y + rE1[j].y);
                az += pk0 * (rA0[j].z + rC0[j].z + rE0[j].z)
                    + pk1 * (rA1[j].z + rC1[j].z + rE1[j].z);
                aw += pk0 * (rA0[j].w + rC0[j].w + rE0[j].w)
                    + pk1 * (rA1[j].w + rC1[j].w + rE1[j].w);
            }
            const int vo = vbase + (s + 4) * 8192;   // refill slot j (OOB-free)
            rA0[j] = bl0(dKb, vo); rA1[j] = bl1(dKb, vo);
            rC0[j] = bl0(dDb, vo); rC1[j] = bl1(dDb, vo);
            rE0[j] = bl0(dEb, vo); rE1[j] = bl1(dEb, vo);
        }
    }
    // Drain dangling refills before their dest regs can be reallocated.
    asm volatile("s_waitcnt vmcnt(0)" ::: "memory");
    __builtin_amdgcn_sched_barrier(0);

    // ---- Cross-wave column reduction ----
    __syncthreads();
    {
        float* rr = &red[(w << 1) + ri][c4];
        rr[0] = ax; rr[1] = ay; rr[2] = az; rr[3] = aw;
    }
    __syncthreads();
    if (t < 32) {
        float4 r = {0.f, 0.f, 0.f, 0.f};
        #pragma unroll
        for (int j = 0; j < 8; ++j) {
            r.x += red[j][t * 4 + 0];
            r.y += red[j][t * 4 + 1];
            r.z += red[j][t * 4 + 2];
            r.w += red[j][t * 4 + 3];
        }
        *(float4*)(out + (size_t)bq * H + t * 4) = r;
    }
}

// ---------------------------------------------------------------------------
extern "C" void kernel_launch(void* const* d_in, const int* in_sizes, int n_in,
                              void* d_out, int out_size, void* d_ws, size_t ws_size,
                              hipStream_t stream)
{
    const float* queries   = (const float*)d_in[0];
    const float* keys      = (const float*)d_in[1];
    const int*   time_mask = (const int*)d_in[2];
    // d_in[3] attn_mask unused: it is exactly triu(ones, k=1), i.e. (k > q)
    const float* tK  = (const float*)d_in[4];
    const float* tV  = (const float*)d_in[5];
    const float* dK  = (const float*)d_in[6];
    const float* dV  = (const float*)d_in[7];
    const float* apK = (const float*)d_in[8];
    const float* apV = (const float*)d_in[9];
    const float* Wq  = (const float*)d_in[10];
    const float* bqv = (const float*)d_in[11];
    const float* Wk  = (const float*)d_in[12];
    const float* bkv = (const float*)d_in[13];
    const float* Wv  = (const float*)d_in[14];
    const float* bvv = (const float*)d_in[15];

    float* Qs  = (float*)d_ws;                 // [B*L*H]
    float* KpK = Qs + (size_t)B * L * H;       // [B*L*H]
    float* VpV = KpK + (size_t)B * L * H;      // [B*L*H]  (total 2.46 MB)
    float* outp = (float*)d_out;

    hipLaunchKernelGGL(tama_proj, dim3(3 * (B * L) / 8), dim3(256), 0, stream,
                       queries, keys, apK, apV, Wq, bqv, Wk, bkv, Wv, bvv,
                       Qs, KpK, VpV);
    hipLaunchKernelGGL(tama_attn, dim3(B * L), dim3(256), 0, stream,
                       Qs, KpK, VpV, time_mask, tK, tV, dK, dV, outp);
}